// Round 1
// baseline (818.247 us; speedup 1.0000x reference)
//
#include <hip/hip_runtime.h>

#define NIMG 16
#define NC 3
#define H 256
#define W 256
#define NS 25          // 5x5 per-pixel kernel
#define TH 32
#define TW 64
#define SRH (TH + 10)  // avg/max region: mask halo(2) + conv halo(3) each side
#define SRW (TW + 10)
#define MRH (TH + 4)   // mask / blur_info region: fac halo(2) each side
#define MRW (TW + 4)
#define NTHREADS 256
#define PIX_PER_THREAD ((TH * TW) / NTHREADS)  // 8

__global__ __launch_bounds__(NTHREADS, 2)
void reblur_fused(const float* __restrict__ blur_info,
                  const float* __restrict__ pp0,
                  const float* __restrict__ pp1,
                  const float* __restrict__ pp2,
                  const float* __restrict__ wt0,
                  const float* __restrict__ wt1,
                  const float* __restrict__ wt2,
                  float* __restrict__ out)
{
    __shared__ float s_avg[SRH * SRW];
    __shared__ float s_mx[SRH * SRW];
    __shared__ float mask_l[MRH * MRW];
    __shared__ float blur_l[NC * MRH * MRW];
    __shared__ float wts[3][98];   // [branch][2*49] (avg weights, then max weights)

    const int tid = threadIdx.x;
    const int n  = blockIdx.z;
    const int h0 = blockIdx.y * TH;
    const int w0 = blockIdx.x * TW;

    // conv weights -> LDS (tiny)
    for (int i = tid; i < 3 * 98; i += NTHREADS) {
        int b = i / 98, j = i % 98;
        const float* wp = (b == 0) ? wt0 : (b == 1) ? wt1 : wt2;
        wts[b][j] = wp[j];
    }
    // blur_info tile with +-2 halo -> LDS (zero-padded), reused across branches
    for (int i = tid; i < NC * MRH * MRW; i += NTHREADS) {
        int c  = i / (MRH * MRW);
        int rr = (i / MRW) % MRH;
        int cc = i % MRW;
        int gh = h0 - 2 + rr, gw = w0 - 2 + cc;
        float v = 0.f;
        if ((unsigned)gh < H && (unsigned)gw < W)
            v = blur_info[((size_t)(n * NC + c) * H + gh) * W + gw];
        blur_l[i] = v;
    }

    float acc[PIX_PER_THREAD][NC];
    #pragma unroll
    for (int k = 0; k < PIX_PER_THREAD; ++k)
        #pragma unroll
        for (int c = 0; c < NC; ++c) acc[k][c] = 0.f;

    const float* pps[3] = {pp0, pp1, pp2};

    for (int b = 0; b < 3; ++b) {
        const float* pp = pps[b] + (size_t)n * NS * H * W;

        // ---- step 1: per-pixel channel avg & max over the 42x74 halo region
        for (int i = tid; i < SRH * SRW; i += NTHREADS) {
            int rr = i / SRW, cc = i % SRW;
            int gh = h0 - 5 + rr, gw = w0 - 5 + cc;
            float sum = 0.f, mx = 0.f;   // out-of-image => conv zero-padding
            if ((unsigned)gh < H && (unsigned)gw < W) {
                const float* p = pp + gh * W + gw;
                float v0 = p[0];
                sum = v0; mx = v0;
                #pragma unroll
                for (int s = 1; s < NS; ++s) {
                    float v = p[(size_t)s * H * W];
                    sum += v; mx = fmaxf(mx, v);
                }
                sum *= (1.f / 25.f);
            }
            s_avg[i] = sum;
            s_mx[i]  = mx;
        }
        __syncthreads();

        // ---- step 2: 7x7 conv + sigmoid -> mask over 36x68 region.
        // Register-blocked: each work item computes 4 vertically adjacent
        // pixels, sharing the 7-wide row reads (35 LDS reads/px vs 196).
        for (int wi = tid; wi < (MRH / 4) * MRW; wi += NTHREADS) {
            int rb = wi / MRW, cc = wi % MRW;
            int r0 = rb * 4;
            float a4[4] = {0.f, 0.f, 0.f, 0.f};
            #pragma unroll
            for (int j = 0; j < 10; ++j) {     // 10 input rows cover 4 outputs
                float av[7], mv[7];
                #pragma unroll
                for (int t = 0; t < 7; ++t) {
                    av[t] = s_avg[(r0 + j) * SRW + cc + t];
                    mv[t] = s_mx[(r0 + j) * SRW + cc + t];
                }
                const int klo = (j - 6) > 0 ? (j - 6) : 0;
                const int khi = j < 3 ? j : 3;
                #pragma unroll
                for (int k = klo; k <= khi; ++k) {
                    const int wr = (j - k) * 7;
                    #pragma unroll
                    for (int t = 0; t < 7; ++t)
                        a4[k] += av[t] * wts[b][wr + t] + mv[t] * wts[b][49 + wr + t];
                }
            }
            #pragma unroll
            for (int k = 0; k < 4; ++k)
                mask_l[(r0 + k) * MRW + cc] = 1.f / (1.f + __expf(-a4[k]));
        }
        __syncthreads();

        // ---- step 3: sharp + per-pixel 5x5 adaptive filter, accumulate.
        // perpix center values re-read from global (fresh in L2/L3).
        for (int k = 0; k < PIX_PER_THREAD; ++k) {
            int oi = tid + k * NTHREADS;
            int r = oi / TW, cc = oi % TW;
            const float* pk = pp + (size_t)(h0 + r) * W + (w0 + cc);
            float mc = mask_l[(r + 2) * MRW + cc + 2];
            float omc = 1.f - mc;
            float fb0 = blur_l[0 * MRH * MRW + (r + 2) * MRW + cc + 2] * omc;
            float fb1 = blur_l[1 * MRH * MRW + (r + 2) * MRW + cc + 2] * omc;
            float fb2 = blur_l[2 * MRH * MRW + (r + 2) * MRW + cc + 2] * omc;
            #pragma unroll
            for (int s = 0; s < NS; ++s) {
                const int dh = s / 5, dw = s % 5;
                float pkv = pk[(size_t)s * H * W];
                float pm = pkv * mask_l[(r + dh) * MRW + cc + dw];
                fb0 += pm * blur_l[0 * MRH * MRW + (r + dh) * MRW + cc + dw];
                fb1 += pm * blur_l[1 * MRH * MRW + (r + dh) * MRW + cc + dw];
                fb2 += pm * blur_l[2 * MRH * MRW + (r + dh) * MRW + cc + dw];
            }
            acc[k][0] += fb0; acc[k][1] += fb1; acc[k][2] += fb2;
        }
        // No barrier needed here: next step-1 writes s bufs (readers barriered
        // after step 2); next step-2's mask_l writes are fenced by the
        // post-step-1 barrier, after which all step-3 reads have completed.
    }

    const float inv3 = 1.f / 3.f;
    for (int k = 0; k < PIX_PER_THREAD; ++k) {
        int oi = tid + k * NTHREADS;
        int r = oi / TW, cc = oi % TW;
        #pragma unroll
        for (int c = 0; c < NC; ++c)
            out[((size_t)(n * NC + c) * H + h0 + r) * W + w0 + cc] = acc[k][c] * inv3;
    }
}

extern "C" void kernel_launch(void* const* d_in, const int* in_sizes, int n_in,
                              void* d_out, int out_size, void* d_ws, size_t ws_size,
                              hipStream_t stream) {
    dim3 grid(W / TW, H / TH, NIMG);   // 4 x 8 x 16 = 512 blocks
    reblur_fused<<<grid, NTHREADS, 0, stream>>>(
        (const float*)d_in[0],
        (const float*)d_in[1], (const float*)d_in[2], (const float*)d_in[3],
        (const float*)d_in[4], (const float*)d_in[5], (const float*)d_in[6],
        (float*)d_out);
}